// Round 19
// baseline (2015.248 us; speedup 1.0000x reference)
//
#include <hip/hip_runtime.h>
#include <hip/hip_bf16.h>
#include <math.h>

#define BB 4
#define TT 1024
#define DD 1024
#define HH 16
#define HDIM 64
#define FFD 4096
#define VV 32000
#define LL 6
#define BT (BB * TT)

typedef __bf16 bf16;
typedef bf16 bf16x8 __attribute__((ext_vector_type(8)));
typedef bf16 bf16x4 __attribute__((ext_vector_type(4)));
typedef float f32x4 __attribute__((ext_vector_type(4)));

__device__ __forceinline__ void gload16(const void* g, void* l) {
    __builtin_amdgcn_global_load_lds((__attribute__((address_space(1))) unsigned int*)(g),
                                     (__attribute__((address_space(3))) unsigned int*)(l),
                                     16, 0, 0);
}

// ---------------- embedding ----------------
__global__ __launch_bounds__(256) void embed_k(const int* __restrict__ idx,
                                               const float* __restrict__ tok,
                                               const float* __restrict__ pos,
                                               float* __restrict__ x) {
    int row = blockIdx.x;
    int tid = threadIdx.x;
    int t = row & (TT - 1);
    int token = idx[row];
    float4 a = *(const float4*)(tok + (size_t)token * DD + tid * 4);
    float4 p = *(const float4*)(pos + (size_t)t * DD + tid * 4);
    *(float4*)(x + (size_t)row * DD + tid * 4) =
        make_float4(a.x + p.x, a.y + p.y, a.z + p.z, a.w + p.w);
}

// ---------------- f32 -> bf16 conversion (weights) ----------------
__global__ __launch_bounds__(256) void cvt_bf16_k(const float* __restrict__ in,
                                                  bf16* __restrict__ out, long n) {
    long i0 = ((long)blockIdx.x * 256 + threadIdx.x) * 8;
    long stride = (long)gridDim.x * 256 * 8;
    for (long i = i0; i < n; i += stride) {
        float4 v0 = *(const float4*)(in + i);
        float4 v1 = *(const float4*)(in + i + 4);
        bf16x8 o;
        o[0] = (bf16)v0.x; o[1] = (bf16)v0.y; o[2] = (bf16)v0.z; o[3] = (bf16)v0.w;
        o[4] = (bf16)v1.x; o[5] = (bf16)v1.y; o[6] = (bf16)v1.z; o[7] = (bf16)v1.w;
        *(bf16x8*)(out + i) = o;
    }
}

// ---------------- layernorm: f32 in, bf16 out ----------------
__global__ __launch_bounds__(256) void layernorm_k(const float* __restrict__ in,
                                                   bf16* __restrict__ out,
                                                   const float* __restrict__ g,
                                                   const float* __restrict__ b) {
    __shared__ float red[256];
    int row = blockIdx.x;
    int tid = threadIdx.x;
    const float* ip = in + (size_t)row * DD;
    float4 v = *(const float4*)(ip + tid * 4);

    float s = v.x + v.y + v.z + v.w;
    red[tid] = s; __syncthreads();
    for (int st = 128; st > 0; st >>= 1) { if (tid < st) red[tid] += red[tid + st]; __syncthreads(); }
    float mu = red[0] * (1.0f / DD);
    __syncthreads();

    float d0 = v.x - mu, d1 = v.y - mu, d2 = v.z - mu, d3 = v.w - mu;
    red[tid] = d0 * d0 + d1 * d1 + d2 * d2 + d3 * d3; __syncthreads();
    for (int st = 128; st > 0; st >>= 1) { if (tid < st) red[tid] += red[tid + st]; __syncthreads(); }
    float var = red[0] * (1.0f / DD);
    float rs = rsqrtf(var + 1e-5f);

    float4 gv = *(const float4*)(g + tid * 4);
    float4 bv = *(const float4*)(b + tid * 4);
    bf16x4 o;
    o[0] = (bf16)(d0 * rs * gv.x + bv.x);
    o[1] = (bf16)(d1 * rs * gv.y + bv.y);
    o[2] = (bf16)(d2 * rs * gv.z + bv.z);
    o[3] = (bf16)(d3 * rs * gv.w + bv.w);
    *(bf16x4*)(out + (size_t)row * DD + tid * 4) = o;
}

// ======== 256x256 GEMM, 4-phase / 2-barrier schedule (round-16 best) ========
template <bool BIAS, bool GELU, bool OBF>
__global__ __launch_bounds__(512, 2) void gemm_256(const bf16* __restrict__ A,
                                                   const bf16* __restrict__ W,
                                                   const float* __restrict__ bias,
                                                   void* __restrict__ Cv,
                                                   int M, int N, int K) {
    __shared__ char lds[2 * 65536];
    const int tid = threadIdx.x;
    const int lane = tid & 63, wave = tid >> 6;
    const int c = lane & 15, g = lane >> 4;

    const int nm = M >> 8;
    const int nwg = gridDim.x;
    const int wgid = (blockIdx.x & 7) * (nwg >> 3) + (blockIdx.x >> 3);
    const int m0 = (wgid % nm) * 256, n0 = (wgid / nm) * 256;
    const int wm = wave >> 2, wn = wave & 3;   // 2 x 4 waves, 128x64 each

    const int srow = tid >> 2;
    const int lq = (tid & 3) ^ ((tid >> 3) & 3);
    const bf16* Asrc = A + (size_t)(m0 + srow) * K + lq * 8;
    const bf16* Bsrc = W + (size_t)(n0 + srow) * K + lq * 8;
    const size_t K128 = (size_t)128 * K;

    const int key = (c >> 1) & 3;
    const int rdA = (wm * 128 + c) * 64 + ((g ^ key) * 16);
    const int rdB = 32768 + (wn * 64 + c) * 64 + ((g ^ key) * 16);

    f32x4 acc[8][4] = {};
    const int NT = K >> 6;
    const int NH = 4 * NT;

#define STAGEH(H)                                                             \
    if ((H) < NH) {                                                           \
        const int t2_ = (H) >> 2, h_ = (H) & 3;                               \
        const bf16* s_ = ((h_ & 1) ? Bsrc : Asrc) + (size_t)t2_ * 64 + (h_ >> 1) * 32; \
        char* d_ = lds + (t2_ & 1) * 65536 + (h_ & 1) * 32768 + (h_ >> 1) * 16384 + tid * 16; \
        gload16(s_, d_);                                                      \
        gload16(s_ + K128, d_ + 8192);                                        \
    }

#define MFMA16(base)                                                          \
    __builtin_amdgcn_s_setprio(1);                                            \
    _Pragma("unroll")                                                         \
    for (int fi = 0; fi < 4; ++fi) {                                          \
        _Pragma("unroll")                                                     \
        for (int fj = 0; fj < 4; ++fj)                                        \
            acc[(base) + fi][fj] = __builtin_amdgcn_mfma_f32_16x16x32_bf16(   \
                bA[fi], bB[fj], acc[(base) + fi][fj], 0, 0, 0);               \
    }                                                                         \
    __builtin_amdgcn_s_setprio(0);

    STAGEH(0); STAGEH(1); STAGEH(2); STAGEH(3); STAGEH(4);
    asm volatile("s_waitcnt vmcnt(6)" ::: "memory");
    __builtin_amdgcn_sched_barrier(0);
    __builtin_amdgcn_s_barrier();
    __builtin_amdgcn_sched_barrier(0);

    for (int kt = 0; kt < NT; ++kt) {
        const char* bp = lds + (kt & 1) * 65536;
        bf16x8 bA[4], bB[4];
        // ---- P0: ks0, fi 0-3 ----
#pragma unroll
        for (int fj = 0; fj < 4; ++fj) bB[fj] = *(const bf16x8*)(bp + rdB + fj * 1024);
#pragma unroll
        for (int fi = 0; fi < 4; ++fi) bA[fi] = *(const bf16x8*)(bp + rdA + fi * 1024);
        STAGEH(4 * kt + 5);
        asm volatile("s_waitcnt lgkmcnt(0)" ::: "memory");
        __builtin_amdgcn_sched_barrier(0);
        MFMA16(0)
        // ---- P1: ks0, fi 4-7 ----
#pragma unroll
        for (int fi = 0; fi < 4; ++fi) bA[fi] = *(const bf16x8*)(bp + rdA + (4 + fi) * 1024);
        STAGEH(4 * kt + 6);
        asm volatile("s_waitcnt lgkmcnt(0)" ::: "memory");
        __builtin_amdgcn_sched_barrier(0);
        MFMA16(4)
        if (kt + 1 < NT) { asm volatile("s_waitcnt vmcnt(6)" ::: "memory"); }
        else             { asm volatile("s_waitcnt vmcnt(0)" ::: "memory"); }
        __builtin_amdgcn_sched_barrier(0);
        __builtin_amdgcn_s_barrier();      // B1: ks0 reads done (WAR); ks1 resident
        __builtin_amdgcn_sched_barrier(0);
        // ---- P2: ks1, fi 0-3 ----
#pragma unroll
        for (int fj = 0; fj < 4; ++fj) bB[fj] = *(const bf16x8*)(bp + rdB + 16384 + fj * 1024);
#pragma unroll
        for (int fi = 0; fi < 4; ++fi) bA[fi] = *(const bf16x8*)(bp + rdA + 16384 + fi * 1024);
        STAGEH(4 * kt + 7);
        asm volatile("s_waitcnt lgkmcnt(0)" ::: "memory");
        __builtin_amdgcn_sched_barrier(0);
        MFMA16(0)
        // ---- P3: ks1, fi 4-7 ----
#pragma unroll
        for (int fi = 0; fi < 4; ++fi) bA[fi] = *(const bf16x8*)(bp + rdA + 16384 + (4 + fi) * 1024);
        STAGEH(4 * kt + 8);
        asm volatile("s_waitcnt lgkmcnt(0)" ::: "memory");
        __builtin_amdgcn_sched_barrier(0);
        MFMA16(4)
        if (kt + 2 < NT)      { asm volatile("s_waitcnt vmcnt(6)" ::: "memory"); }
        else if (kt + 2 == NT){ asm volatile("s_waitcnt vmcnt(4)" ::: "memory"); }
        __builtin_amdgcn_sched_barrier(0);
        __builtin_amdgcn_s_barrier();      // B3: ks1 reads done; next tile ks0 resident
        __builtin_amdgcn_sched_barrier(0);
    }
#undef STAGEH
#undef MFMA16

    const int orow  = m0 + wm * 128 + g * 4;
    const int ocol0 = n0 + wn * 64 + c;
#pragma unroll
    for (int fj = 0; fj < 4; ++fj) {
        const int col = ocol0 + fj * 16;
        float bs = 0.f;
        if (BIAS) bs = bias[col];
#pragma unroll
        for (int fi = 0; fi < 8; ++fi) {
#pragma unroll
            for (int r = 0; r < 4; ++r) {
                int row = orow + fi * 16 + r;
                float v = acc[fi][fj][r] + bs;
                if (GELU) v = 0.5f * v * (1.0f + erff(v * 0.70710678118654752f));
                if (OBF) ((bf16*)Cv)[(size_t)row * N + col] = (bf16)v;
                else     ((float*)Cv)[(size_t)row * N + col] = v;
            }
        }
    }
}

// ======== 128x128 GEMM, 2-phase / 2-barrier schedule; 64KB LDS -> 2 blocks/CU ====
// Non-ADD path stores nontemporal (bypass L3: keeps A/W resident, no write-alloc).
template <bool ADD, bool BIAS>
__global__ __launch_bounds__(256, 2) void gemm_128p(const bf16* __restrict__ A,
                                                    const bf16* __restrict__ W,
                                                    const float* __restrict__ bias,
                                                    float* __restrict__ C,
                                                    int M, int N, int K) {
    __shared__ char lds[2 * 32768];
    const int tid = threadIdx.x;
    const int lane = tid & 63, wave = tid >> 6;
    const int c = lane & 15, g = lane >> 4;

    const int nm = M >> 7;
    const int nwg = gridDim.x;
    const int wgid = (blockIdx.x & 7) * (nwg >> 3) + (blockIdx.x >> 3);
    const int m0 = (wgid % nm) * 128, n0 = (wgid / nm) * 128;
    const int wm = wave >> 1, wn = wave & 1;   // 2 x 2 waves, 64x64 each

    const int srow = tid >> 2;
    const int lq = (tid & 3) ^ ((tid >> 3) & 3);
    const bf16* Asrc = A + (size_t)(m0 + srow) * K + lq * 8;
    const bf16* Bsrc = W + (size_t)(n0 + srow) * K + lq * 8;
    const size_t K64 = (size_t)64 * K;

    const int key = (c >> 1) & 3;
    const int rdA = (wm * 64 + c) * 64 + ((g ^ key) * 16);
    const int rdB = 16384 + (wn * 64 + c) * 64 + ((g ^ key) * 16);

    f32x4 acc[4][4] = {};
    const int NT = K >> 6;
    const int NH = 4 * NT;

#define STAGEH(H)                                                             \
    if ((H) < NH) {                                                           \
        const int t2_ = (H) >> 2, h_ = (H) & 3;                               \
        const bf16* s_ = ((h_ & 1) ? Bsrc : Asrc) + (size_t)t2_ * 64 + (h_ >> 1) * 32; \
        char* d_ = lds + (t2_ & 1) * 32768 + (h_ & 1) * 16384 + (h_ >> 1) * 8192 + tid * 16; \
        gload16(s_, d_);                                                      \
        gload16(s_ + K64, d_ + 4096);                                         \
    }

#define MFMA16()                                                              \
    __builtin_amdgcn_s_setprio(1);                                            \
    _Pragma("unroll")                                                         \
    for (int fi = 0; fi < 4; ++fi) {                                          \
        _Pragma("unroll")                                                     \
        for (int fj = 0; fj < 4; ++fj)                                       \
            acc[fi][fj] = __builtin_amdgcn_mfma_f32_16x16x32_bf16(            \
                bA[fi], bB[fj], acc[fi][fj], 0, 0, 0);                        \
    }                                                                         \
    __builtin_amdgcn_s_setprio(0);

    STAGEH(0); STAGEH(1); STAGEH(2); STAGEH(3); STAGEH(4); STAGEH(5);
    asm volatile("s_waitcnt vmcnt(8)" ::: "memory");
    __builtin_amdgcn_sched_barrier(0);
    __builtin_amdgcn_s_barrier();
    __builtin_amdgcn_sched_barrier(0);

    for (int kt = 0; kt < NT; ++kt) {
        const char* bp = lds + (kt & 1) * 32768;
        bf16x8 bA[4], bB[4];
        // ---- phase A: ks0 ----
#pragma unroll
        for (int fj = 0; fj < 4; ++fj) bB[fj] = *(const bf16x8*)(bp + rdB + fj * 1024);
#pragma unroll
        for (int fi = 0; fi < 4; ++fi) bA[fi] = *(const bf16x8*)(bp + rdA + fi * 1024);
        STAGEH(4 * kt + 6); STAGEH(4 * kt + 7);
        asm volatile("s_waitcnt lgkmcnt(0)" ::: "memory");
        __builtin_amdgcn_sched_barrier(0);
        MFMA16()
        if (kt + 1 < NT) { asm volatile("s_waitcnt vmcnt(8)" ::: "memory"); }
        else             { asm volatile("s_waitcnt vmcnt(0)" ::: "memory"); }
        __builtin_amdgcn_sched_barrier(0);
        __builtin_amdgcn_s_barrier();      // ks0 reads done (WAR); ks1 resident
        __builtin_amdgcn_sched_barrier(0);
        // ---- phase B: ks1 ----
#pragma unroll
        for (int fj = 0; fj < 4; ++fj) bB[fj] = *(const bf16x8*)(bp + rdB + 8192 + fj * 1024);
#pragma unroll
        for (int fi = 0; fi < 4; ++fi) bA[fi] = *(const bf16x8*)(bp + rdA + 8192 + fi * 1024);
        STAGEH(4 * kt + 8); STAGEH(4 * kt + 9);
        asm volatile("s_waitcnt lgkmcnt(0)" ::: "memory");
        __builtin_amdgcn_sched_barrier(0);
        MFMA16()
        if (kt + 2 < NT)       { asm volatile("s_waitcnt vmcnt(8)" ::: "memory"); }
        else if (kt + 2 == NT) { asm volatile("s_waitcnt vmcnt(4)" ::: "memory"); }
        __builtin_amdgcn_sched_barrier(0);
        __builtin_amdgcn_s_barrier();      // ks1 reads done; next tile ks0 resident
        __builtin_amdgcn_sched_barrier(0);
    }
#undef STAGEH
#undef MFMA16

    const int orow  = m0 + wm * 64 + g * 4;
    const int ocol0 = n0 + wn * 64 + c;
#pragma unroll
    for (int fj = 0; fj < 4; ++fj) {
        const int col = ocol0 + fj * 16;
        float bs = 0.f;
        if (BIAS) bs = bias[col];
#pragma unroll
        for (int fi = 0; fi < 4; ++fi) {
#pragma unroll
            for (int r = 0; r < 4; ++r) {
                int row = orow + fi * 16 + r;
                float v = acc[fi][fj][r] + bs;
                float* p = C + (size_t)row * N + col;
                if (ADD) *p += v;
                else     __builtin_nontemporal_store(v, p);
            }
        }
    }
}

// ---------------- V transpose prep v2: coalesced via LDS ----------------
__global__ __launch_bounds__(256) void vprep_k(const bf16* __restrict__ qkv,
                                               bf16* __restrict__ Vt) {
    __shared__ bf16 Vls[64 * 72];
    const int tid = threadIdx.x;
    const int t0 = blockIdx.x * 64;
    const int h = blockIdx.y, b = blockIdx.z;
    const int row = tid >> 3, ch = tid & 7;

    const bf16* src = qkv + ((size_t)(b * TT + t0 + row)) * 3072 + 2048 + h * 64 + ch * 8;
    bf16x8 v0 = *(const bf16x8*)(src);
    bf16x8 v1 = *(const bf16x8*)(src + (size_t)32 * 3072);
#pragma unroll
    for (int j = 0; j < 8; ++j) {
        Vls[(ch * 8 + j) * 72 + row]      = v0[j];
        Vls[(ch * 8 + j) * 72 + row + 32] = v1[j];
    }
    __syncthreads();

    const int dr = tid >> 3;
    bf16* dst = Vt + ((size_t)((b * HH + h) * 64 + dr)) * 1024 + t0 + ch * 8;
    bf16x8 o0 = *(const bf16x8*)(Vls + dr * 72 + ch * 8);
    bf16x8 o1 = *(const bf16x8*)(Vls + (dr + 32) * 72 + ch * 8);
    *(bf16x8*)(dst) = o0;
    *(bf16x8*)(dst + (size_t)32 * 1024) = o1;
}

// ---------------- flash attention v3: QBLK=128 (8 waves), dbuf, LPT ----------------
__global__ __launch_bounds__(512) void fattn_k(const bf16* __restrict__ qkv,
                                               const bf16* __restrict__ Vt,
                                               bf16* __restrict__ y) {
    __shared__ bf16 Ks[2][64 * 64];
    __shared__ bf16 Vs[2][64 * 64];
    __shared__ bf16 Ps[8][16 * 72];
    const int tid = threadIdx.x, lane = tid & 63, wave = tid >> 6;
    const int g = lane >> 4, c = lane & 15;
    const int q0 = (gridDim.x - 1 - blockIdx.x) * 128;   // LPT: longest first
    const int h = blockIdx.y, b = blockIdx.z;
    const size_t qbase = (size_t)b * TT * 3072;

    const int qrow = q0 + wave * 16 + c;
    const bf16* qp = qkv + qbase + (size_t)qrow * 3072 + h * 64;
    bf16x8 qf0 = *(const bf16x8*)(qp + g * 8);
    bf16x8 qf1 = *(const bf16x8*)(qp + 32 + g * 8);

    const int srow = tid >> 3;
    const int lq = (tid & 7) ^ (srow & 7);
    const bf16* Ksrc = qkv + qbase + 1024 + h * 64 + (size_t)srow * 3072 + lq * 8;
    const bf16* Vsrc = Vt + ((size_t)(b * HH + h) * 64 + srow) * 1024 + lq * 8;

    float mO[4] = {-1e30f, -1e30f, -1e30f, -1e30f};
    float lO[4] = {0.f, 0.f, 0.f, 0.f};
    f32x4 acc[4] = {};

    bf16* pw = Ps[wave];
    const int ntiles = (q0 >> 6) + 2;
    const int qg0 = q0 + wave * 16 + 4 * g;
    const int cs = c & 7;

#define STAGE_KV(t_, buf_)                                                        \
    {                                                                             \
        const int kk_ = (t_) * 64;                                                \
        gload16(Ksrc + (size_t)kk_ * 3072, (char*)Ks[buf_] + tid * 16);           \
        gload16(Vsrc + kk_,                (char*)Vs[buf_] + tid * 16);           \
    }

    STAGE_KV(0, 0)

    for (int t = 0; t < ntiles; ++t) {
        const int k0 = t * 64;
        if (t + 1 < ntiles) {
            STAGE_KV(t + 1, (t + 1) & 1)
            asm volatile("s_waitcnt vmcnt(2)" ::: "memory");
        } else {
            asm volatile("s_waitcnt vmcnt(0)" ::: "memory");
        }
        __builtin_amdgcn_sched_barrier(0);
        __builtin_amdgcn_s_barrier();
        __builtin_amdgcn_sched_barrier(0);

        const bf16* kb = Ks[t & 1];
        const bf16* vb = Vs[t & 1];

        f32x4 s[4] = {};
#pragma unroll
        for (int j = 0; j < 4; ++j) {
            const bf16* kr = kb + (16 * j + c) * 64;
            bf16x8 kf0 = *(const bf16x8*)(kr + ((g ^ cs) * 8));
            bf16x8 kf1 = *(const bf16x8*)(kr + (((4 + g) ^ cs) * 8));
            s[j] = __builtin_amdgcn_mfma_f32_16x16x32_bf16(qf0, kf0, s[j], 0, 0, 0);
            s[j] = __builtin_amdgcn_mfma_f32_16x16x32_bf16(qf1, kf1, s[j], 0, 0, 0);
        }

        float mt_[4];
        bool need = false;
#pragma unroll
        for (int r = 0; r < 4; ++r) {
            const int qg = qg0 + r;
            float a0 = s[0][r] * 0.125f, a1 = s[1][r] * 0.125f;
            float a2 = s[2][r] * 0.125f, a3 = s[3][r] * 0.125f;
            if (k0 + c > qg)      a0 = -1e30f;
            if (k0 + 16 + c > qg) a1 = -1e30f;
            if (k0 + 32 + c > qg) a2 = -1e30f;
            if (k0 + 48 + c > qg) a3 = -1e30f;
            s[0][r] = a0; s[1][r] = a1; s[2][r] = a2; s[3][r] = a3;
            float mt = fmaxf(fmaxf(a0, a1), fmaxf(a2, a3));
            mt = fmaxf(mt, __shfl_xor(mt, 1));
            mt = fmaxf(mt, __shfl_xor(mt, 2));
            mt = fmaxf(mt, __shfl_xor(mt, 4));
            mt = fmaxf(mt, __shfl_xor(mt, 8));
            mt_[r] = mt;
            need |= (mt > mO[r]);
        }
        if (__any(need)) {
#pragma unroll
            for (int r = 0; r < 4; ++r) {
                float mn = fmaxf(mO[r], mt_[r]);
                float sc = __expf(mO[r] - mn);
                mO[r] = mn;
                lO[r] *= sc;
                acc[0][r] *= sc; acc[1][r] *= sc; acc[2][r] *= sc; acc[3][r] *= sc;
            }
        }
#pragma unroll
        for (int r = 0; r < 4; ++r) {
            float e0 = __expf(s[0][r] - mO[r]);
            float e1 = __expf(s[1][r] - mO[r]);
            float e2 = __expf(s[2][r] - mO[r]);
            float e3 = __expf(s[3][r] - mO[r]);
            lO[r] += (e0 + e1) + (e2 + e3);
            bf16* pr = pw + (4 * g + r) * 72;
            pr[c] = (bf16)e0; pr[16 + c] = (bf16)e1;
            pr[32 + c] = (bf16)e2; pr[48 + c] = (bf16)e3;
        }

#pragma unroll
        for (int ks = 0; ks < 2; ++ks) {
            bf16x8 pf = *(const bf16x8*)(pw + c * 72 + ks * 32 + g * 8);
#pragma unroll
            for (int jb = 0; jb < 4; ++jb) {
                const int d = 16 * jb + c;
                bf16x8 vf = *(const bf16x8*)(vb + d * 64 + (((ks * 4 + g) ^ cs) * 8));
                acc[jb] = __builtin_amdgcn_mfma_f32_16x16x32_bf16(pf, vf, acc[jb], 0, 0, 0);
            }
        }
        __builtin_amdgcn_s_barrier();
        __builtin_amdgcn_sched_barrier(0);
    }
#undef STAGE_KV

#pragma unroll
    for (int r = 0; r < 4; ++r) {
        float l = lO[r];
        l += __shfl_xor(l, 1);
        l += __shfl_xor(l, 2);
        l += __shfl_xor(l, 4);
        l += __shfl_xor(l, 8);
        float invl = 1.0f / l;
        size_t orow = (size_t)(b * TT + qg0 + r) * DD + h * 64;
#pragma unroll
        for (int jb = 0; jb < 4; ++jb)
            y[orow + jb * 16 + c] = (bf16)(acc[jb][r] * invl);
    }
}

// ---------------- host ----------------
extern "C" void kernel_launch(void* const* d_in, const int* in_sizes, int n_in,
                              void* d_out, int out_size, void* d_ws, size_t ws_size,
                              hipStream_t stream) {
    const int*   idx     = (const int*)d_in[0];
    const float* tok_emb = (const float*)d_in[1];
    const float* pos_emb = (const float*)d_in[2];
    const float* ln1_g   = (const float*)d_in[3];
    const float* ln1_b   = (const float*)d_in[4];
    const float* qkv_w   = (const float*)d_in[5];
    const float* proj_w  = (const float*)d_in[6];
    const float* ln2_g   = (const float*)d_in[7];
    const float* ln2_b   = (const float*)d_in[8];
    const float* mlp_w1  = (const float*)d_in[9];
    const float* mlp_b1  = (const float*)d_in[10];
    const float* mlp_w2  = (const float*)d_in[11];
    const float* mlp_b2  = (const float*)d_in[12];
    const float* lnf_g   = (const float*)d_in[13];
    const float* lnf_b   = (const float*)d_in[14];
    const float* head_w  = (const float*)d_in[15];
    float* out = (float*)d_out;

    char* ws = (char*)d_ws;
    float* x      = (float*)ws;
    bf16*  qkv_bf = (bf16*)(ws + (16ull << 20));
    bf16*  Vt     = (bf16*)(ws + (40ull << 20));
    bf16*  h_bf   = (bf16*)(ws + (48ull << 20));
    bf16*  y_bf   = (bf16*)(ws + (56ull << 20));
    bf16*  ff_bf  = (bf16*)(ws + (64ull << 20));
    bf16*  wbuf   = (bf16*)(ws + (96ull << 20));
    bf16*  hw_bf  = (bf16*)(ws + (56ull << 20));

    embed_k<<<BT, 256, 0, stream>>>(idx, tok_emb, pos_emb, x);

    for (int l = 0; l < LL; ++l) {
        layernorm_k<<<BT, 256, 0, stream>>>(x, h_bf, ln1_g + (size_t)l * DD, ln1_b + (size_t)l * DD);
        cvt_bf16_k<<<2048, 256, 0, stream>>>(qkv_w + (size_t)l * 3 * DD * DD, wbuf, (long)3 * DD * DD);
        gemm_256<false, false, true><<<(BT / 256) * (3 * DD / 256), 512, 0, stream>>>(
            h_bf, wbuf, nullptr, qkv_bf, BT, 3 * DD, DD);
        vprep_k<<<dim3(TT / 64, HH, BB), 256, 0, stream>>>(qkv_bf, Vt);
        fattn_k<<<dim3(TT / 128, HH, BB), 512, 0, stream>>>(qkv_bf, Vt, y_bf);
        cvt_bf16_k<<<2048, 256, 0, stream>>>(proj_w + (size_t)l * DD * DD, wbuf, (long)DD * DD);
        gemm_128p<true, false><<<(BT / 128) * (DD / 128), 256, 0, stream>>>(
            y_bf, wbuf, nullptr, x, BT, DD, DD);
        layernorm_k<<<BT, 256, 0, stream>>>(x, h_bf, ln2_g + (size_t)l * DD, ln2_b + (size_t)l * DD);
        cvt_bf16_k<<<2048, 256, 0, stream>>>(mlp_w1 + (size_t)l * FFD * DD, wbuf, (long)FFD * DD);
        gemm_256<true, true, true><<<(BT / 256) * (FFD / 256), 512, 0, stream>>>(
            h_bf, wbuf, mlp_b1 + (size_t)l * FFD, ff_bf, BT, FFD, DD);
        cvt_bf16_k<<<2048, 256, 0, stream>>>(mlp_w2 + (size_t)l * DD * FFD, wbuf, (long)DD * FFD);
        gemm_128p<true, true><<<(BT / 128) * (DD / 128), 256, 0, stream>>>(
            ff_bf, wbuf, mlp_b2 + (size_t)l * DD, x, BT, DD, FFD);
    }

    layernorm_k<<<BT, 256, 0, stream>>>(x, h_bf, lnf_g, lnf_b);
    cvt_bf16_k<<<4096, 256, 0, stream>>>(head_w, hw_bf, (long)VV * DD);
    gemm_128p<false, false><<<(BT / 128) * (VV / 128), 256, 0, stream>>>(
        h_bf, hw_bf, nullptr, out, BT, VV, DD);
}

// Round 20
// 1927.804 us; speedup vs baseline: 1.0454x; 1.0454x over previous
//
#include <hip/hip_runtime.h>
#include <hip/hip_bf16.h>
#include <math.h>

#define BB 4
#define TT 1024
#define DD 1024
#define HH 16
#define HDIM 64
#define FFD 4096
#define VV 32000
#define LL 6
#define BT (BB * TT)

typedef __bf16 bf16;
typedef bf16 bf16x8 __attribute__((ext_vector_type(8)));
typedef bf16 bf16x4 __attribute__((ext_vector_type(4)));
typedef float f32x4 __attribute__((ext_vector_type(4)));

__device__ __forceinline__ void gload16(const void* g, void* l) {
    __builtin_amdgcn_global_load_lds((__attribute__((address_space(1))) unsigned int*)(g),
                                     (__attribute__((address_space(3))) unsigned int*)(l),
                                     16, 0, 0);
}

// ---------------- embedding ----------------
__global__ __launch_bounds__(256) void embed_k(const int* __restrict__ idx,
                                               const float* __restrict__ tok,
                                               const float* __restrict__ pos,
                                               float* __restrict__ x) {
    int row = blockIdx.x;
    int tid = threadIdx.x;
    int t = row & (TT - 1);
    int token = idx[row];
    float4 a = *(const float4*)(tok + (size_t)token * DD + tid * 4);
    float4 p = *(const float4*)(pos + (size_t)t * DD + tid * 4);
    *(float4*)(x + (size_t)row * DD + tid * 4) =
        make_float4(a.x + p.x, a.y + p.y, a.z + p.z, a.w + p.w);
}

// ---------------- f32 -> bf16 conversion (weights) ----------------
__global__ __launch_bounds__(256) void cvt_bf16_k(const float* __restrict__ in,
                                                  bf16* __restrict__ out, long n) {
    long i0 = ((long)blockIdx.x * 256 + threadIdx.x) * 8;
    long stride = (long)gridDim.x * 256 * 8;
    for (long i = i0; i < n; i += stride) {
        float4 v0 = *(const float4*)(in + i);
        float4 v1 = *(const float4*)(in + i + 4);
        bf16x8 o;
        o[0] = (bf16)v0.x; o[1] = (bf16)v0.y; o[2] = (bf16)v0.z; o[3] = (bf16)v0.w;
        o[4] = (bf16)v1.x; o[5] = (bf16)v1.y; o[6] = (bf16)v1.z; o[7] = (bf16)v1.w;
        *(bf16x8*)(out + i) = o;
    }
}

// ---------------- layernorm: f32 in, bf16 out ----------------
__global__ __launch_bounds__(256) void layernorm_k(const float* __restrict__ in,
                                                   bf16* __restrict__ out,
                                                   const float* __restrict__ g,
                                                   const float* __restrict__ b) {
    __shared__ float red[256];
    int row = blockIdx.x;
    int tid = threadIdx.x;
    const float* ip = in + (size_t)row * DD;
    float4 v = *(const float4*)(ip + tid * 4);

    float s = v.x + v.y + v.z + v.w;
    red[tid] = s; __syncthreads();
    for (int st = 128; st > 0; st >>= 1) { if (tid < st) red[tid] += red[tid + st]; __syncthreads(); }
    float mu = red[0] * (1.0f / DD);
    __syncthreads();

    float d0 = v.x - mu, d1 = v.y - mu, d2 = v.z - mu, d3 = v.w - mu;
    red[tid] = d0 * d0 + d1 * d1 + d2 * d2 + d3 * d3; __syncthreads();
    for (int st = 128; st > 0; st >>= 1) { if (tid < st) red[tid] += red[tid + st]; __syncthreads(); }
    float var = red[0] * (1.0f / DD);
    float rs = rsqrtf(var + 1e-5f);

    float4 gv = *(const float4*)(g + tid * 4);
    float4 bv = *(const float4*)(b + tid * 4);
    bf16x4 o;
    o[0] = (bf16)(d0 * rs * gv.x + bv.x);
    o[1] = (bf16)(d1 * rs * gv.y + bv.y);
    o[2] = (bf16)(d2 * rs * gv.z + bv.z);
    o[3] = (bf16)(d3 * rs * gv.w + bv.w);
    *(bf16x4*)(out + (size_t)row * DD + tid * 4) = o;
}

// ======== 256x256 GEMM, 4-phase / 2-barrier schedule (round-16/18 best) ========
// Non-OBF store path is nontemporal (head logits: write-once, bypass L2/L3).
template <bool BIAS, bool GELU, bool OBF>
__global__ __launch_bounds__(512, 2) void gemm_256(const bf16* __restrict__ A,
                                                   const bf16* __restrict__ W,
                                                   const float* __restrict__ bias,
                                                   void* __restrict__ Cv,
                                                   int M, int N, int K) {
    __shared__ char lds[2 * 65536];
    const int tid = threadIdx.x;
    const int lane = tid & 63, wave = tid >> 6;
    const int c = lane & 15, g = lane >> 4;

    const int nm = M >> 8;
    const int nwg = gridDim.x;
    const int wgid = (blockIdx.x & 7) * (nwg >> 3) + (blockIdx.x >> 3);
    const int m0 = (wgid % nm) * 256, n0 = (wgid / nm) * 256;
    const int wm = wave >> 2, wn = wave & 3;   // 2 x 4 waves, 128x64 each

    const int srow = tid >> 2;
    const int lq = (tid & 3) ^ ((tid >> 3) & 3);
    const bf16* Asrc = A + (size_t)(m0 + srow) * K + lq * 8;
    const bf16* Bsrc = W + (size_t)(n0 + srow) * K + lq * 8;
    const size_t K128 = (size_t)128 * K;

    const int key = (c >> 1) & 3;
    const int rdA = (wm * 128 + c) * 64 + ((g ^ key) * 16);
    const int rdB = 32768 + (wn * 64 + c) * 64 + ((g ^ key) * 16);

    f32x4 acc[8][4] = {};
    const int NT = K >> 6;
    const int NH = 4 * NT;

#define STAGEH(H)                                                             \
    if ((H) < NH) {                                                           \
        const int t2_ = (H) >> 2, h_ = (H) & 3;                               \
        const bf16* s_ = ((h_ & 1) ? Bsrc : Asrc) + (size_t)t2_ * 64 + (h_ >> 1) * 32; \
        char* d_ = lds + (t2_ & 1) * 65536 + (h_ & 1) * 32768 + (h_ >> 1) * 16384 + tid * 16; \
        gload16(s_, d_);                                                      \
        gload16(s_ + K128, d_ + 8192);                                        \
    }

#define MFMA16(base)                                                          \
    __builtin_amdgcn_s_setprio(1);                                            \
    _Pragma("unroll")                                                         \
    for (int fi = 0; fi < 4; ++fi) {                                          \
        _Pragma("unroll")                                                     \
        for (int fj = 0; fj < 4; ++fj)                                        \
            acc[(base) + fi][fj] = __builtin_amdgcn_mfma_f32_16x16x32_bf16(   \
                bA[fi], bB[fj], acc[(base) + fi][fj], 0, 0, 0);               \
    }                                                                         \
    __builtin_amdgcn_s_setprio(0);

    STAGEH(0); STAGEH(1); STAGEH(2); STAGEH(3); STAGEH(4);
    asm volatile("s_waitcnt vmcnt(6)" ::: "memory");
    __builtin_amdgcn_sched_barrier(0);
    __builtin_amdgcn_s_barrier();
    __builtin_amdgcn_sched_barrier(0);

    for (int kt = 0; kt < NT; ++kt) {
        const char* bp = lds + (kt & 1) * 65536;
        bf16x8 bA[4], bB[4];
        // ---- P0: ks0, fi 0-3 ----
#pragma unroll
        for (int fj = 0; fj < 4; ++fj) bB[fj] = *(const bf16x8*)(bp + rdB + fj * 1024);
#pragma unroll
        for (int fi = 0; fi < 4; ++fi) bA[fi] = *(const bf16x8*)(bp + rdA + fi * 1024);
        STAGEH(4 * kt + 5);
        asm volatile("s_waitcnt lgkmcnt(0)" ::: "memory");
        __builtin_amdgcn_sched_barrier(0);
        MFMA16(0)
        // ---- P1: ks0, fi 4-7 ----
#pragma unroll
        for (int fi = 0; fi < 4; ++fi) bA[fi] = *(const bf16x8*)(bp + rdA + (4 + fi) * 1024);
        STAGEH(4 * kt + 6);
        asm volatile("s_waitcnt lgkmcnt(0)" ::: "memory");
        __builtin_amdgcn_sched_barrier(0);
        MFMA16(4)
        if (kt + 1 < NT) { asm volatile("s_waitcnt vmcnt(6)" ::: "memory"); }
        else             { asm volatile("s_waitcnt vmcnt(0)" ::: "memory"); }
        __builtin_amdgcn_sched_barrier(0);
        __builtin_amdgcn_s_barrier();      // B1: ks0 reads done (WAR); ks1 resident
        __builtin_amdgcn_sched_barrier(0);
        // ---- P2: ks1, fi 0-3 ----
#pragma unroll
        for (int fj = 0; fj < 4; ++fj) bB[fj] = *(const bf16x8*)(bp + rdB + 16384 + fj * 1024);
#pragma unroll
        for (int fi = 0; fi < 4; ++fi) bA[fi] = *(const bf16x8*)(bp + rdA + 16384 + fi * 1024);
        STAGEH(4 * kt + 7);
        asm volatile("s_waitcnt lgkmcnt(0)" ::: "memory");
        __builtin_amdgcn_sched_barrier(0);
        MFMA16(0)
        // ---- P3: ks1, fi 4-7 ----
#pragma unroll
        for (int fi = 0; fi < 4; ++fi) bA[fi] = *(const bf16x8*)(bp + rdA + 16384 + (4 + fi) * 1024);
        STAGEH(4 * kt + 8);
        asm volatile("s_waitcnt lgkmcnt(0)" ::: "memory");
        __builtin_amdgcn_sched_barrier(0);
        MFMA16(4)
        if (kt + 2 < NT)      { asm volatile("s_waitcnt vmcnt(6)" ::: "memory"); }
        else if (kt + 2 == NT){ asm volatile("s_waitcnt vmcnt(4)" ::: "memory"); }
        __builtin_amdgcn_sched_barrier(0);
        __builtin_amdgcn_s_barrier();      // B3: ks1 reads done; next tile ks0 resident
        __builtin_amdgcn_sched_barrier(0);
    }
#undef STAGEH
#undef MFMA16

    const int orow  = m0 + wm * 128 + g * 4;
    const int ocol0 = n0 + wn * 64 + c;
#pragma unroll
    for (int fj = 0; fj < 4; ++fj) {
        const int col = ocol0 + fj * 16;
        float bs = 0.f;
        if (BIAS) bs = bias[col];
#pragma unroll
        for (int fi = 0; fi < 8; ++fi) {
#pragma unroll
            for (int r = 0; r < 4; ++r) {
                int row = orow + fi * 16 + r;
                float v = acc[fi][fj][r] + bs;
                if (GELU) v = 0.5f * v * (1.0f + erff(v * 0.70710678118654752f));
                if (OBF) ((bf16*)Cv)[(size_t)row * N + col] = (bf16)v;
                else     __builtin_nontemporal_store(v, (float*)Cv + (size_t)row * N + col);
            }
        }
    }
}

// ======== 128x128 GEMM, 2-phase / 2-barrier schedule (proj/mlp2, ADD path) ========
template <bool ADD, bool BIAS>
__global__ __launch_bounds__(256, 2) void gemm_128p(const bf16* __restrict__ A,
                                                    const bf16* __restrict__ W,
                                                    const float* __restrict__ bias,
                                                    float* __restrict__ C,
                                                    int M, int N, int K) {
    __shared__ char lds[2 * 32768];
    const int tid = threadIdx.x;
    const int lane = tid & 63, wave = tid >> 6;
    const int c = lane & 15, g = lane >> 4;

    const int nm = M >> 7;
    const int nwg = gridDim.x;
    const int wgid = (blockIdx.x & 7) * (nwg >> 3) + (blockIdx.x >> 3);
    const int m0 = (wgid % nm) * 128, n0 = (wgid / nm) * 128;
    const int wm = wave >> 1, wn = wave & 1;   // 2 x 2 waves, 64x64 each

    const int srow = tid >> 2;
    const int lq = (tid & 3) ^ ((tid >> 3) & 3);
    const bf16* Asrc = A + (size_t)(m0 + srow) * K + lq * 8;
    const bf16* Bsrc = W + (size_t)(n0 + srow) * K + lq * 8;
    const size_t K64 = (size_t)64 * K;

    const int key = (c >> 1) & 3;
    const int rdA = (wm * 64 + c) * 64 + ((g ^ key) * 16);
    const int rdB = 16384 + (wn * 64 + c) * 64 + ((g ^ key) * 16);

    f32x4 acc[4][4] = {};
    const int NT = K >> 6;
    const int NH = 4 * NT;

#define STAGEH(H)                                                             \
    if ((H) < NH) {                                                           \
        const int t2_ = (H) >> 2, h_ = (H) & 3;                               \
        const bf16* s_ = ((h_ & 1) ? Bsrc : Asrc) + (size_t)t2_ * 64 + (h_ >> 1) * 32; \
        char* d_ = lds + (t2_ & 1) * 32768 + (h_ & 1) * 16384 + (h_ >> 1) * 8192 + tid * 16; \
        gload16(s_, d_);                                                      \
        gload16(s_ + K64, d_ + 4096);                                         \
    }

#define MFMA16()                                                              \
    __builtin_amdgcn_s_setprio(1);                                            \
    _Pragma("unroll")                                                         \
    for (int fi = 0; fi < 4; ++fi) {                                          \
        _Pragma("unroll")                                                     \
        for (int fj = 0; fj < 4; ++fj)                                       \
            acc[fi][fj] = __builtin_amdgcn_mfma_f32_16x16x32_bf16(            \
                bA[fi], bB[fj], acc[fi][fj], 0, 0, 0);                        \
    }                                                                         \
    __builtin_amdgcn_s_setprio(0);

    STAGEH(0); STAGEH(1); STAGEH(2); STAGEH(3); STAGEH(4); STAGEH(5);
    asm volatile("s_waitcnt vmcnt(8)" ::: "memory");
    __builtin_amdgcn_sched_barrier(0);
    __builtin_amdgcn_s_barrier();
    __builtin_amdgcn_sched_barrier(0);

    for (int kt = 0; kt < NT; ++kt) {
        const char* bp = lds + (kt & 1) * 32768;
        bf16x8 bA[4], bB[4];
        // ---- phase A: ks0 ----
#pragma unroll
        for (int fj = 0; fj < 4; ++fj) bB[fj] = *(const bf16x8*)(bp + rdB + fj * 1024);
#pragma unroll
        for (int fi = 0; fi < 4; ++fi) bA[fi] = *(const bf16x8*)(bp + rdA + fi * 1024);
        STAGEH(4 * kt + 6); STAGEH(4 * kt + 7);
        asm volatile("s_waitcnt lgkmcnt(0)" ::: "memory");
        __builtin_amdgcn_sched_barrier(0);
        MFMA16()
        if (kt + 1 < NT) { asm volatile("s_waitcnt vmcnt(8)" ::: "memory"); }
        else             { asm volatile("s_waitcnt vmcnt(0)" ::: "memory"); }
        __builtin_amdgcn_sched_barrier(0);
        __builtin_amdgcn_s_barrier();      // ks0 reads done (WAR); ks1 resident
        __builtin_amdgcn_sched_barrier(0);
        // ---- phase B: ks1 ----
#pragma unroll
        for (int fj = 0; fj < 4; ++fj) bB[fj] = *(const bf16x8*)(bp + rdB + 8192 + fj * 1024);
#pragma unroll
        for (int fi = 0; fi < 4; ++fi) bA[fi] = *(const bf16x8*)(bp + rdA + 8192 + fi * 1024);
        STAGEH(4 * kt + 8); STAGEH(4 * kt + 9);
        asm volatile("s_waitcnt lgkmcnt(0)" ::: "memory");
        __builtin_amdgcn_sched_barrier(0);
        MFMA16()
        if (kt + 2 < NT)       { asm volatile("s_waitcnt vmcnt(8)" ::: "memory"); }
        else if (kt + 2 == NT) { asm volatile("s_waitcnt vmcnt(4)" ::: "memory"); }
        __builtin_amdgcn_sched_barrier(0);
        __builtin_amdgcn_s_barrier();      // ks1 reads done; next tile ks0 resident
        __builtin_amdgcn_sched_barrier(0);
    }
#undef STAGEH
#undef MFMA16

    const int orow  = m0 + wm * 64 + g * 4;
    const int ocol0 = n0 + wn * 64 + c;
#pragma unroll
    for (int fj = 0; fj < 4; ++fj) {
        const int col = ocol0 + fj * 16;
        float bs = 0.f;
        if (BIAS) bs = bias[col];
#pragma unroll
        for (int fi = 0; fi < 4; ++fi) {
#pragma unroll
            for (int r = 0; r < 4; ++r) {
                int row = orow + fi * 16 + r;
                float v = acc[fi][fj][r] + bs;
                float* p = C + (size_t)row * N + col;
                if (ADD) *p += v;
                else     __builtin_nontemporal_store(v, p);
            }
        }
    }
}

// ---------------- V transpose prep v2: coalesced via LDS ----------------
__global__ __launch_bounds__(256) void vprep_k(const bf16* __restrict__ qkv,
                                               bf16* __restrict__ Vt) {
    __shared__ bf16 Vls[64 * 72];
    const int tid = threadIdx.x;
    const int t0 = blockIdx.x * 64;
    const int h = blockIdx.y, b = blockIdx.z;
    const int row = tid >> 3, ch = tid & 7;

    const bf16* src = qkv + ((size_t)(b * TT + t0 + row)) * 3072 + 2048 + h * 64 + ch * 8;
    bf16x8 v0 = *(const bf16x8*)(src);
    bf16x8 v1 = *(const bf16x8*)(src + (size_t)32 * 3072);
#pragma unroll
    for (int j = 0; j < 8; ++j) {
        Vls[(ch * 8 + j) * 72 + row]      = v0[j];
        Vls[(ch * 8 + j) * 72 + row + 32] = v1[j];
    }
    __syncthreads();

    const int dr = tid >> 3;
    bf16* dst = Vt + ((size_t)((b * HH + h) * 64 + dr)) * 1024 + t0 + ch * 8;
    bf16x8 o0 = *(const bf16x8*)(Vls + dr * 72 + ch * 8);
    bf16x8 o1 = *(const bf16x8*)(Vls + (dr + 32) * 72 + ch * 8);
    *(bf16x8*)(dst) = o0;
    *(bf16x8*)(dst + (size_t)32 * 1024) = o1;
}

// ---------------- flash attention v3: QBLK=128 (8 waves), dbuf, LPT ----------------
__global__ __launch_bounds__(512) void fattn_k(const bf16* __restrict__ qkv,
                                               const bf16* __restrict__ Vt,
                                               bf16* __restrict__ y) {
    __shared__ bf16 Ks[2][64 * 64];
    __shared__ bf16 Vs[2][64 * 64];
    __shared__ bf16 Ps[8][16 * 72];
    const int tid = threadIdx.x, lane = tid & 63, wave = tid >> 6;
    const int g = lane >> 4, c = lane & 15;
    const int q0 = (gridDim.x - 1 - blockIdx.x) * 128;   // LPT: longest first
    const int h = blockIdx.y, b = blockIdx.z;
    const size_t qbase = (size_t)b * TT * 3072;

    const int qrow = q0 + wave * 16 + c;
    const bf16* qp = qkv + qbase + (size_t)qrow * 3072 + h * 64;
    bf16x8 qf0 = *(const bf16x8*)(qp + g * 8);
    bf16x8 qf1 = *(const bf16x8*)(qp + 32 + g * 8);

    const int srow = tid >> 3;
    const int lq = (tid & 7) ^ (srow & 7);
    const bf16* Ksrc = qkv + qbase + 1024 + h * 64 + (size_t)srow * 3072 + lq * 8;
    const bf16* Vsrc = Vt + ((size_t)(b * HH + h) * 64 + srow) * 1024 + lq * 8;

    float mO[4] = {-1e30f, -1e30f, -1e30f, -1e30f};
    float lO[4] = {0.f, 0.f, 0.f, 0.f};
    f32x4 acc[4] = {};

    bf16* pw = Ps[wave];
    const int ntiles = (q0 >> 6) + 2;
    const int qg0 = q0 + wave * 16 + 4 * g;
    const int cs = c & 7;

#define STAGE_KV(t_, buf_)                                                        \
    {                                                                             \
        const int kk_ = (t_) * 64;                                                \
        gload16(Ksrc + (size_t)kk_ * 3072, (char*)Ks[buf_] + tid * 16);           \
        gload16(Vsrc + kk_,                (char*)Vs[buf_] + tid * 16);           \
    }

    STAGE_KV(0, 0)

    for (int t = 0; t < ntiles; ++t) {
        const int k0 = t * 64;
        if (t + 1 < ntiles) {
            STAGE_KV(t + 1, (t + 1) & 1)
            asm volatile("s_waitcnt vmcnt(2)" ::: "memory");
        } else {
            asm volatile("s_waitcnt vmcnt(0)" ::: "memory");
        }
        __builtin_amdgcn_sched_barrier(0);
        __builtin_amdgcn_s_barrier();
        __builtin_amdgcn_sched_barrier(0);

        const bf16* kb = Ks[t & 1];
        const bf16* vb = Vs[t & 1];

        f32x4 s[4] = {};
#pragma unroll
        for (int j = 0; j < 4; ++j) {
            const bf16* kr = kb + (16 * j + c) * 64;
            bf16x8 kf0 = *(const bf16x8*)(kr + ((g ^ cs) * 8));
            bf16x8 kf1 = *(const bf16x8*)(kr + (((4 + g) ^ cs) * 8));
            s[j] = __builtin_amdgcn_mfma_f32_16x16x32_bf16(qf0, kf0, s[j], 0, 0, 0);
            s[j] = __builtin_amdgcn_mfma_f32_16x16x32_bf16(qf1, kf1, s[j], 0, 0, 0);
        }

        float mt_[4];
        bool need = false;
#pragma unroll
        for (int r = 0; r < 4; ++r) {
            const int qg = qg0 + r;
            float a0 = s[0][r] * 0.125f, a1 = s[1][r] * 0.125f;
            float a2 = s[2][r] * 0.125f, a3 = s[3][r] * 0.125f;
            if (k0 + c > qg)      a0 = -1e30f;
            if (k0 + 16 + c > qg) a1 = -1e30f;
            if (k0 + 32 + c > qg) a2 = -1e30f;
            if (k0 + 48 + c > qg) a3 = -1e30f;
            s[0][r] = a0; s[1][r] = a1; s[2][r] = a2; s[3][r] = a3;
            float mt = fmaxf(fmaxf(a0, a1), fmaxf(a2, a3));
            mt = fmaxf(mt, __shfl_xor(mt, 1));
            mt = fmaxf(mt, __shfl_xor(mt, 2));
            mt = fmaxf(mt, __shfl_xor(mt, 4));
            mt = fmaxf(mt, __shfl_xor(mt, 8));
            mt_[r] = mt;
            need |= (mt > mO[r]);
        }
        if (__any(need)) {
#pragma unroll
            for (int r = 0; r < 4; ++r) {
                float mn = fmaxf(mO[r], mt_[r]);
                float sc = __expf(mO[r] - mn);
                mO[r] = mn;
                lO[r] *= sc;
                acc[0][r] *= sc; acc[1][r] *= sc; acc[2][r] *= sc; acc[3][r] *= sc;
            }
        }
#pragma unroll
        for (int r = 0; r < 4; ++r) {
            float e0 = __expf(s[0][r] - mO[r]);
            float e1 = __expf(s[1][r] - mO[r]);
            float e2 = __expf(s[2][r] - mO[r]);
            float e3 = __expf(s[3][r] - mO[r]);
            lO[r] += (e0 + e1) + (e2 + e3);
            bf16* pr = pw + (4 * g + r) * 72;
            pr[c] = (bf16)e0; pr[16 + c] = (bf16)e1;
            pr[32 + c] = (bf16)e2; pr[48 + c] = (bf16)e3;
        }

#pragma unroll
        for (int ks = 0; ks < 2; ++ks) {
            bf16x8 pf = *(const bf16x8*)(pw + c * 72 + ks * 32 + g * 8);
#pragma unroll
            for (int jb = 0; jb < 4; ++jb) {
                const int d = 16 * jb + c;
                bf16x8 vf = *(const bf16x8*)(vb + d * 64 + (((ks * 4 + g) ^ cs) * 8));
                acc[jb] = __builtin_amdgcn_mfma_f32_16x16x32_bf16(pf, vf, acc[jb], 0, 0, 0);
            }
        }
        __builtin_amdgcn_s_barrier();
        __builtin_amdgcn_sched_barrier(0);
    }
#undef STAGE_KV

#pragma unroll
    for (int r = 0; r < 4; ++r) {
        float l = lO[r];
        l += __shfl_xor(l, 1);
        l += __shfl_xor(l, 2);
        l += __shfl_xor(l, 4);
        l += __shfl_xor(l, 8);
        float invl = 1.0f / l;
        size_t orow = (size_t)(b * TT + qg0 + r) * DD + h * 64;
#pragma unroll
        for (int jb = 0; jb < 4; ++jb)
            y[orow + jb * 16 + c] = (bf16)(acc[jb][r] * invl);
    }
}

// ---------------- host ----------------
extern "C" void kernel_launch(void* const* d_in, const int* in_sizes, int n_in,
                              void* d_out, int out_size, void* d_ws, size_t ws_size,
                              hipStream_t stream) {
    const int*   idx     = (const int*)d_in[0];
    const float* tok_emb = (const float*)d_in[1];
    const float* pos_emb = (const float*)d_in[2];
    const float* ln1_g   = (const float*)d_in[3];
    const float* ln1_b   = (const float*)d_in[4];
    const float* qkv_w   = (const float*)d_in[5];
    const float* proj_w  = (const float*)d_in[6];
    const float* ln2_g   = (const float*)d_in[7];
    const float* ln2_b   = (const float*)d_in[8];
    const float* mlp_w1  = (const float*)d_in[9];
    const float* mlp_b1  = (const float*)d_in[10];
    const float* mlp_w2  = (const float*)d_in[11];
    const float* mlp_b2  = (const float*)d_in[12];
    const float* lnf_g   = (const float*)d_in[13];
    const float* lnf_b   = (const float*)d_in[14];
    const float* head_w  = (const float*)d_in[15];
    float* out = (float*)d_out;

    char* ws = (char*)d_ws;
    float* x      = (float*)ws;
    bf16*  qkv_bf = (bf16*)(ws + (16ull << 20));
    bf16*  Vt     = (bf16*)(ws + (40ull << 20));
    bf16*  h_bf   = (bf16*)(ws + (48ull << 20));
    bf16*  y_bf   = (bf16*)(ws + (56ull << 20));
    bf16*  ff_bf  = (bf16*)(ws + (64ull << 20));
    bf16*  wbuf   = (bf16*)(ws + (96ull << 20));
    bf16*  hw_bf  = (bf16*)(ws + (56ull << 20));

    embed_k<<<BT, 256, 0, stream>>>(idx, tok_emb, pos_emb, x);

    for (int l = 0; l < LL; ++l) {
        layernorm_k<<<BT, 256, 0, stream>>>(x, h_bf, ln1_g + (size_t)l * DD, ln1_b + (size_t)l * DD);
        cvt_bf16_k<<<2048, 256, 0, stream>>>(qkv_w + (size_t)l * 3 * DD * DD, wbuf, (long)3 * DD * DD);
        gemm_256<false, false, true><<<(BT / 256) * (3 * DD / 256), 512, 0, stream>>>(
            h_bf, wbuf, nullptr, qkv_bf, BT, 3 * DD, DD);
        vprep_k<<<dim3(TT / 64, HH, BB), 256, 0, stream>>>(qkv_bf, Vt);
        fattn_k<<<dim3(TT / 128, HH, BB), 512, 0, stream>>>(qkv_bf, Vt, y_bf);
        cvt_bf16_k<<<2048, 256, 0, stream>>>(proj_w + (size_t)l * DD * DD, wbuf, (long)DD * DD);
        gemm_128p<true, false><<<(BT / 128) * (DD / 128), 256, 0, stream>>>(
            y_bf, wbuf, nullptr, x, BT, DD, DD);
        layernorm_k<<<BT, 256, 0, stream>>>(x, h_bf, ln2_g + (size_t)l * DD, ln2_b + (size_t)l * DD);
        cvt_bf16_k<<<2048, 256, 0, stream>>>(mlp_w1 + (size_t)l * FFD * DD, wbuf, (long)FFD * DD);
        gemm_256<true, true, true><<<(BT / 256) * (FFD / 256), 512, 0, stream>>>(
            h_bf, wbuf, mlp_b1 + (size_t)l * FFD, ff_bf, BT, FFD, DD);
        cvt_bf16_k<<<2048, 256, 0, stream>>>(mlp_w2 + (size_t)l * DD * FFD, wbuf, (long)DD * FFD);
        gemm_128p<true, true><<<(BT / 128) * (DD / 128), 256, 0, stream>>>(
            ff_bf, wbuf, mlp_b2 + (size_t)l * DD, x, BT, DD, FFD);
    }

    layernorm_k<<<BT, 256, 0, stream>>>(x, h_bf, lnf_g, lnf_b);
    cvt_bf16_k<<<4096, 256, 0, stream>>>(head_w, hw_bf, (long)VV * DD);
    gemm_256<false, false, false><<<(BT / 256) * (VV / 256), 512, 0, stream>>>(
        h_bf, hw_bf, nullptr, out, BT, VV, DD);
}